// Round 7
// baseline (85.082 us; speedup 1.0000x reference)
//
#include <hip/hip_runtime.h>

#define N_MICS  192
#define OVERLAP 1024
#define WINDOW  524288
#define ROWLEN  (OVERLAP + WINDOW)
#define BLK     256
#define SPT     4
#define NGRP    4
#define MPG     (N_MICS / NGRP)        // 48 mics per group

#define RFL_I(x) __builtin_amdgcn_readfirstlane(x)
#define RFL_F(x) __uint_as_float(__builtin_amdgcn_readfirstlane(__float_as_uint(x)))

// 4-float vector with 4-byte alignment (dword-aligned global_load_dwordx4)
typedef float f4a4 __attribute__((ext_vector_type(4), aligned(4)));

// ---------------- delay preamble (exact f32 replication of numpy) ---------
__device__ __forceinline__ void compute_delays(
    const float* __restrict__ pos, const float* __restrict__ mic_pos,
    float* s_dist, int* s_off, float* s_df, int tid)
{
    if (tid < N_MICS) {
        float dx = __fsub_rn(pos[0], mic_pos[tid * 3 + 0]);
        float dy = __fsub_rn(pos[1], mic_pos[tid * 3 + 1]);
        float dz = __fsub_rn(pos[2], mic_pos[tid * 3 + 2]);
        float ss = __fadd_rn(__fadd_rn(__fmul_rn(dx, dx), __fmul_rn(dy, dy)),
                             __fmul_rn(dz, dz));
        s_dist[tid] = __fsqrt_rn(ss);
    }
    __syncthreads();
    if (tid < N_MICS) {
        float mx = s_dist[0];
        for (int i = 1; i < N_MICS; ++i) mx = fmaxf(mx, s_dist[i]);
        float dd = __fsub_rn(s_dist[tid], mx);              // <= 0
        float delay = __fmul_rn(
                          __fmul_rn(__fdiv_rn(-dd, 343000.0f), 768000.0f),
                          0.0625f);                         // /16 exact
        int di = (int)delay;                                // trunc, delay >= 0
        s_off[tid] = tid * ROWLEN + OVERLAP - di;
        s_df[tid]  = __fsub_rn(delay, (float)di);
    }
    __syncthreads();
}

// ---- partial: group g of 48 mics, R6 gather pattern, 32 waves/CU ---------
__global__ __launch_bounds__(BLK) void tdbf_partial(
    const float* __restrict__ pos,
    const float* __restrict__ mic_pos,
    const float* __restrict__ buf,
    float* __restrict__ ws)
{
    __shared__ float s_dist[N_MICS];
    __shared__ int   s_off[N_MICS];
    __shared__ float s_df[N_MICS];
    const int tid = threadIdx.x;
    compute_delays(pos, mic_pos, s_dist, s_off, s_df, tid);

    const int g    = blockIdx.y;
    const int mBeg = g * MPG;
    const int t4   = (blockIdx.x * BLK + tid) * SPT;

    float a0 = 0.f, a1 = 0.f, a2 = 0.f, a3 = 0.f;

    #pragma unroll 6
    for (int mi = 0; mi < MPG; ++mi) {
        const int   off = RFL_I(s_off[mBeg + mi]);
        const float f   = RFL_F(s_df[mBeg + mi]);
        const float* p  = buf + off + t4;
        const float vm1 = p[-1];
        const f4a4  w   = *reinterpret_cast<const f4a4*>(p);
        const float gg  = 1.0f - f;
        a0 = fmaf(w.x, gg, fmaf(vm1, f, a0));
        a1 = fmaf(w.y, gg, fmaf(w.x, f, a1));
        a2 = fmaf(w.z, gg, fmaf(w.y, f, a2));
        a3 = fmaf(w.w, gg, fmaf(w.z, f, a3));
    }

    float4 o; o.x = a0; o.y = a1; o.z = a2; o.w = a3;
    *reinterpret_cast<float4*>(ws + (size_t)g * WINDOW + t4) = o;
}

// ---- reduce: out = (g0+g1+g2+g3)/192 -------------------------------------
__global__ __launch_bounds__(BLK) void tdbf_reduce(
    const float* __restrict__ ws, float* __restrict__ out)
{
    const int i = (blockIdx.x * BLK + threadIdx.x) * 4;
    const float4 x0 = *reinterpret_cast<const float4*>(ws + i);
    const float4 x1 = *reinterpret_cast<const float4*>(ws + (size_t)1 * WINDOW + i);
    const float4 x2 = *reinterpret_cast<const float4*>(ws + (size_t)2 * WINDOW + i);
    const float4 x3 = *reinterpret_cast<const float4*>(ws + (size_t)3 * WINDOW + i);
    const float inv = 1.0f / (float)N_MICS;
    float4 o;
    o.x = (((x0.x + x1.x) + x2.x) + x3.x) * inv;
    o.y = (((x0.y + x1.y) + x2.y) + x3.y) * inv;
    o.z = (((x0.z + x1.z) + x2.z) + x3.z) * inv;
    o.w = (((x0.w + x1.w) + x2.w) + x3.w) * inv;
    *reinterpret_cast<float4*>(out + i) = o;
}

// ---- fallback: proven R6 mono kernel -------------------------------------
__global__ __launch_bounds__(BLK) void tdbf_mono(
    const float* __restrict__ pos,
    const float* __restrict__ mic_pos,
    const float* __restrict__ buf,
    float* __restrict__ out)
{
    __shared__ float s_dist[N_MICS];
    __shared__ int   s_off[N_MICS];
    __shared__ float s_df[N_MICS];
    const int tid = threadIdx.x;
    compute_delays(pos, mic_pos, s_dist, s_off, s_df, tid);

    const int t4 = (blockIdx.x * BLK + tid) * SPT;
    float a0 = 0.f, a1 = 0.f, a2 = 0.f, a3 = 0.f;
    #pragma unroll 6
    for (int m = 0; m < N_MICS; ++m) {
        const int   off = RFL_I(s_off[m]);
        const float f   = RFL_F(s_df[m]);
        const float* p  = buf + off + t4;
        const float vm1 = p[-1];
        const f4a4  w   = *reinterpret_cast<const f4a4*>(p);
        const float gg  = 1.0f - f;
        a0 = fmaf(w.x, gg, fmaf(vm1, f, a0));
        a1 = fmaf(w.y, gg, fmaf(w.x, f, a1));
        a2 = fmaf(w.z, gg, fmaf(w.y, f, a2));
        a3 = fmaf(w.w, gg, fmaf(w.z, f, a3));
    }
    const float inv = 1.0f / (float)N_MICS;
    float4 o; o.x = a0 * inv; o.y = a1 * inv; o.z = a2 * inv; o.w = a3 * inv;
    *reinterpret_cast<float4*>(out + t4) = o;
}

extern "C" void kernel_launch(void* const* d_in, const int* in_sizes, int n_in,
                              void* d_out, int out_size, void* d_ws, size_t ws_size,
                              hipStream_t stream) {
    const float* pos     = (const float*)d_in[0];
    const float* mic_pos = (const float*)d_in[1];
    const float* buf     = (const float*)d_in[2];
    float* out           = (float*)d_out;

    const size_t ws_needed = (size_t)NGRP * WINDOW * sizeof(float);
    if (ws_size >= ws_needed) {
        float* ws = (float*)d_ws;
        dim3 pgrid(WINDOW / (BLK * SPT), NGRP);   // 512 x 4 = 2048 blocks
        tdbf_partial<<<pgrid, dim3(BLK), 0, stream>>>(pos, mic_pos, buf, ws);
        dim3 rgrid(WINDOW / (BLK * 4));           // 512 blocks
        tdbf_reduce<<<rgrid, dim3(BLK), 0, stream>>>(ws, out);
    } else {
        dim3 grid(WINDOW / (BLK * SPT));          // 512 blocks
        tdbf_mono<<<grid, dim3(BLK), 0, stream>>>(pos, mic_pos, buf, out);
    }
}